// Round 11
// baseline (123.553 us; speedup 1.0000x reference)
//
#include <hip/hip_runtime.h>
#include <hip/hip_bf16.h>

#define NN 50000
#define NE 800000
#define HD 128
#define WPAD 136                // transposed-W LDS/global row stride (shorts), 16B-aligned

#define BINSH 9                 // 512 nodes per coarse bin
#define NBINS 98                // ceil(50000/512)
#define BINCAP 9216             // slop capacity (mean 8163, 11.6 sigma)
#define CHUNK 1024              // edges per binplace block (782 blocks)
#define MAXBIN 9216

#define GEMM_BLOCKS ((NN + 63) / 64)          // 782
#define BIN_BLOCKS  ((NE + CHUNK - 1) / CHUNK) // 782

typedef __attribute__((ext_vector_type(8))) short bf16x8;
typedef __attribute__((ext_vector_type(4))) float f32x4;

// f32 -> bf16 round-to-nearest-even
__device__ inline unsigned short f2bf(float f) {
    union { float f; unsigned u; } c; c.f = f;
    unsigned r = c.u + 0x7fff + ((c.u >> 16) & 1);
    return (unsigned short)(r >> 16);
}

__device__ inline float bflo(unsigned u) { return __uint_as_float(u << 16); }
__device__ inline float bfhi(unsigned u) { return __uint_as_float(u & 0xffff0000u); }
__device__ inline float b2f(unsigned short u) { return __uint_as_float(((unsigned)u) << 16); }

// ---------------- prep: cursor init + W^T bf16 + Wb^T bf16 tables ----------------
__global__ __launch_bounds__(256) void k_prep(
        const float* __restrict__ W, const float* __restrict__ Wb, int* cursor,
        unsigned short* __restrict__ Wtg, unsigned short* __restrict__ Wbth) {
    int t = threadIdx.x;
    if (blockIdx.x == 0 && t < NBINS) cursor[t] = t * BINCAP;
    int idx = blockIdx.x * 256 + t;
    if (idx < HD * HD) {
        int h = idx >> 7, c = idx & 127;        // W[h][c]
        Wtg[c * WPAD + h] = f2bf(W[idx]);
        Wbth[c * WPAD + h] = f2bf(Wb[idx]);
    }
}

// ---------------- fused: blocks [0,782) MFMA GEMM, blocks [782,1564) edge binning ----------------
__global__ __launch_bounds__(256) void k_fused1(
        const float* __restrict__ x, const unsigned short* __restrict__ Wtg,
        unsigned short* __restrict__ ybf,
        const int* __restrict__ ei, int* cursor, unsigned* __restrict__ binned) {
    __shared__ union {
        unsigned short Wt[HD * WPAD];           // 34816 B
        struct {
            unsigned stage[CHUNK];
            unsigned char sbin[CHUNK];
            int hist[NBINS], base[NBINS], cur[NBINS], gbase[NBINS];
        } p;
    } sh;
    int t = threadIdx.x;

    if (blockIdx.x < GEMM_BLOCKS) {
        // ---- GEMM: ybf = bf16(x @ W)  (dinv applied later in gather) ----
        int rowBase = blockIdx.x * 64;
        const uint4* src = (const uint4*)Wtg;
        uint4* dst = (uint4*)sh.Wt;
        #pragma unroll
        for (int i = 0; i < 9; ++i) {
            int f = t + i * 256;
            if (f < (HD * WPAD * 2) / 16) dst[f] = src[f];
        }
        __syncthreads();

        int w = t >> 6, lane = t & 63;
        int row = rowBase + w * 16 + (lane & 15);
        int rowc = row < NN ? row : NN - 1;
        int kbase = (lane >> 4) * 8;

        bf16x8 ah[4];
        const float* xrow = &x[(size_t)rowc * HD];
        #pragma unroll
        for (int kk = 0; kk < 4; ++kk) {
            float4 u0 = *(const float4*)(xrow + kk * 32 + kbase);
            float4 u1 = *(const float4*)(xrow + kk * 32 + kbase + 4);
            ah[kk][0] = (short)f2bf(u0.x); ah[kk][1] = (short)f2bf(u0.y);
            ah[kk][2] = (short)f2bf(u0.z); ah[kk][3] = (short)f2bf(u0.w);
            ah[kk][4] = (short)f2bf(u1.x); ah[kk][5] = (short)f2bf(u1.y);
            ah[kk][6] = (short)f2bf(u1.z); ah[kk][7] = (short)f2bf(u1.w);
        }

        f32x4 acc[8];
        #pragma unroll
        for (int ct = 0; ct < 8; ++ct) acc[ct] = (f32x4){0.f, 0.f, 0.f, 0.f};
        #pragma unroll
        for (int kk = 0; kk < 4; ++kk) {
            #pragma unroll
            for (int ct = 0; ct < 8; ++ct) {
                bf16x8 bfr = *(const bf16x8*)&sh.Wt[(ct * 16 + (lane & 15)) * WPAD + kk * 32 + kbase];
                acc[ct] = __builtin_amdgcn_mfma_f32_16x16x32_bf16(ah[kk], bfr, acc[ct], 0, 0, 0);
            }
        }

        int r0 = rowBase + w * 16 + ((lane >> 4) << 2);
        #pragma unroll
        for (int r = 0; r < 4; ++r) {
            int gr = r0 + r;
            if (gr >= NN) continue;
            size_t basei = (size_t)gr * HD;
            #pragma unroll
            for (int ct = 0; ct < 8; ++ct)
                ybf[basei + ct * 16 + (lane & 15)] = f2bf(acc[ct][r]);
        }
    } else {
        // ---- binplace: bin edges by dst>>9, coalesced writes ----
        int e0 = (blockIdx.x - GEMM_BLOCKS) * CHUNK;
        int nE = NE - e0; if (nE > CHUNK) nE = CHUNK;

        if (t < NBINS) sh.p.hist[t] = 0;
        __syncthreads();

        unsigned keys[CHUNK / 256], packs[CHUNK / 256];
        #pragma unroll
        for (int i = 0; i < CHUNK / 256; ++i) {
            int li = i * 256 + t;
            keys[i] = 0xffffffffu;
            if (li < nE) {
                int e = e0 + li;
                unsigned s = (unsigned)ei[e];
                unsigned d = (unsigned)ei[NE + e];
                if (s < NN && d < NN) {
                    keys[i] = d >> BINSH;
                    packs[i] = (s << BINSH) | (d & ((1u << BINSH) - 1));
                    atomicAdd(&sh.p.hist[keys[i]], 1);
                }
            }
        }
        __syncthreads();
        if (t == 0) { int a = 0; for (int b = 0; b < NBINS; ++b) { sh.p.base[b] = a; a += sh.p.hist[b]; } }
        __syncthreads();
        if (t < NBINS) {
            sh.p.cur[t] = sh.p.base[t];
            if (sh.p.hist[t] > 0) sh.p.gbase[t] = atomicAdd(&cursor[t], sh.p.hist[t]);
        }
        __syncthreads();
        #pragma unroll
        for (int i = 0; i < CHUNK / 256; ++i) {
            if (keys[i] != 0xffffffffu) {
                int p = atomicAdd(&sh.p.cur[keys[i]], 1);
                sh.p.stage[p] = packs[i];
                sh.p.sbin[p] = (unsigned char)keys[i];
            }
        }
        __syncthreads();
        int tot = sh.p.cur[NBINS - 1];
        for (int j = t; j < tot; j += 256) {
            unsigned b = sh.p.sbin[j];
            binned[sh.p.gbase[b] + (j - sh.p.base[b])] = sh.p.stage[j];
        }
    }
}

// ---------------- pass 2: per-bin sort -> CSR (u16 src), deg/dinv/rowstart ----------------
__global__ __launch_bounds__(512) void k_csr(
        const unsigned* __restrict__ binned, const int* __restrict__ cursor,
        unsigned short* __restrict__ csr, int* __restrict__ rowstart,
        int* __restrict__ degi, float* __restrict__ dinv) {
    __shared__ unsigned ent[MAXBIN];
    __shared__ unsigned short outv[MAXBIN];
    __shared__ int hist[512], rs[512], cur[512];
    __shared__ int sizes[NBINS];
    int t = threadIdx.x, b = blockIdx.x;

    if (t < NBINS) sizes[t] = cursor[t] - t * BINCAP;
    __syncthreads();
    int bsize = sizes[b]; if (bsize > MAXBIN) bsize = MAXBIN;
    int bstart = 0;
    for (int i = 0; i < b; ++i) bstart += sizes[i];

    for (int j = t; j < bsize; j += 512) ent[j] = binned[b * BINCAP + j];
    if (t < 512) hist[t] = 0;
    __syncthreads();
    for (int j = t; j < bsize; j += 512) atomicAdd(&hist[ent[j] & 511], 1);
    __syncthreads();
    if (t == 0) { int a = 0; for (int k = 0; k < 512; ++k) { rs[k] = a; a += hist[k]; } }
    __syncthreads();
    if (t < 512) {
        cur[t] = rs[t];
        int g = (b << BINSH) + t;
        if (g < NN) {
            rowstart[g] = bstart + rs[t];
            degi[g] = hist[t];
            dinv[g] = rsqrtf((float)(hist[t] + 1));
        }
    }
    __syncthreads();
    for (int j = t; j < bsize; j += 512) {
        unsigned v = ent[j];
        int p = atomicAdd(&cur[v & 511], 1);
        outv[p] = (unsigned short)(v >> BINSH);
    }
    __syncthreads();
    for (int j = t; j < bsize; j += 512) csr[bstart + j] = outv[j];
}

// ---------------- gather: zbf[n] = bf16(dinv[n]*(y[n]*dinv[n] + sum y[s]*dinv[s]) + b) ----------------
// 16 lanes per node, 8 cols (16 B) per lane. Tail-free: clamped indices + zero weights
// keep every memory op 8-deep pipelined (no serial remainder loop).
__global__ __launch_bounds__(256, 8) void k_gather(
        const unsigned short* __restrict__ csr, const int* __restrict__ rowstart,
        const int* __restrict__ degi, const float* __restrict__ dinv,
        const unsigned short* __restrict__ ybf, const float* __restrict__ b,
        unsigned short* __restrict__ zbf) {
    int t = threadIdx.x;
    int n = blockIdx.x * 16 + (t >> 4);
    int lane = t & 15;
    if (n >= NN) return;
    int c = lane * 8;

    float dvn = dinv[n];
    float acc[8];
    {
        uint4 q = *(const uint4*)&ybf[(size_t)n * HD + c];
        acc[0] = bflo(q.x) * dvn; acc[1] = bfhi(q.x) * dvn;
        acc[2] = bflo(q.y) * dvn; acc[3] = bfhi(q.y) * dvn;
        acc[4] = bflo(q.z) * dvn; acc[5] = bfhi(q.z) * dvn;
        acc[6] = bflo(q.w) * dvn; acc[7] = bfhi(q.w) * dvn;
    }
    int beg = rowstart[n];
    int dg = degi[n];
    int nb = (dg + 7) >> 3;     // 8-edge blocks (0 if dg==0)

    for (int ib = 0; ib < nb; ++ib) {
        int i0 = ib * 8;
        int ss[8];
        bool live[8];
        #pragma unroll
        for (int u = 0; u < 8; ++u) {
            int ii = i0 + u;
            live[u] = ii < dg;
            int j = live[u] ? ii : dg - 1;     // clamp (dup of last edge, L1 hit)
            ss[u] = csr[beg + j];
        }
        float dd[8];
        uint4 q[8];
        #pragma unroll
        for (int u = 0; u < 8; ++u) {
            dd[u] = live[u] ? dinv[ss[u]] : 0.f;   // zero weight kills clamped dups
            q[u] = *(const uint4*)&ybf[(size_t)ss[u] * HD + c];
        }
        #pragma unroll
        for (int u = 0; u < 8; ++u) {
            acc[0] += bflo(q[u].x) * dd[u]; acc[1] += bfhi(q[u].x) * dd[u];
            acc[2] += bflo(q[u].y) * dd[u]; acc[3] += bfhi(q[u].y) * dd[u];
            acc[4] += bflo(q[u].z) * dd[u]; acc[5] += bfhi(q[u].z) * dd[u];
            acc[6] += bflo(q[u].w) * dd[u]; acc[7] += bfhi(q[u].w) * dd[u];
        }
    }

    float4 bv0 = *(const float4*)&b[c];
    float4 bv1 = *(const float4*)&b[c + 4];
    unsigned o0 = (unsigned)f2bf(acc[0] * dvn + bv0.x) | ((unsigned)f2bf(acc[1] * dvn + bv0.y) << 16);
    unsigned o1 = (unsigned)f2bf(acc[2] * dvn + bv0.z) | ((unsigned)f2bf(acc[3] * dvn + bv0.w) << 16);
    unsigned o2 = (unsigned)f2bf(acc[4] * dvn + bv1.x) | ((unsigned)f2bf(acc[5] * dvn + bv1.y) << 16);
    unsigned o3 = (unsigned)f2bf(acc[6] * dvn + bv1.z) | ((unsigned)f2bf(acc[7] * dvn + bv1.w) << 16);
    uint4 o = make_uint4(o0, o1, o2, o3);
    *(uint4*)&zbf[(size_t)n * HD + c] = o;
}

// ---------------- MFMA bilinear: t = zbf@Wb (1-pass); pos=<t,z>, neg=<t,z[perm]> ----------------
__global__ __launch_bounds__(256) void k_bilinear(
        const unsigned short* __restrict__ zbf,
        const unsigned short* __restrict__ Wbth,
        const float* __restrict__ bb, const int* __restrict__ perm,
        float* __restrict__ out) {
    __shared__ unsigned short Wth[HD * WPAD];   // Wb^T bf16, 34.8 KB
    int t = threadIdx.x;
    int rowBase = blockIdx.x * 64;

    {
        const uint4* shp = (const uint4*)Wbth;
        uint4* dh = (uint4*)Wth;
        #pragma unroll
        for (int i = 0; i < 9; ++i) {
            int f = t + i * 256;
            if (f < (HD * WPAD * 2) / 16) dh[f] = shp[f];
        }
    }
    __syncthreads();

    int w = t >> 6, lane = t & 63;
    int row = rowBase + w * 16 + (lane & 15);
    int rowc = row < NN ? row : NN - 1;
    int kbase = (lane >> 4) * 8;

    bf16x8 za[4];
    const unsigned short* zrow = &zbf[(size_t)rowc * HD];
    #pragma unroll
    for (int kk = 0; kk < 4; ++kk)
        za[kk] = *(const bf16x8*)&zrow[kk * 32 + kbase];

    f32x4 acc[8];
    #pragma unroll
    for (int ct = 0; ct < 8; ++ct) acc[ct] = (f32x4){0.f, 0.f, 0.f, 0.f};
    #pragma unroll
    for (int kk = 0; kk < 4; ++kk) {
        #pragma unroll
        for (int ct = 0; ct < 8; ++ct) {
            bf16x8 bh = *(const bf16x8*)&Wth[(ct * 16 + (lane & 15)) * WPAD + kk * 32 + kbase];
            acc[ct] = __builtin_amdgcn_mfma_f32_16x16x32_bf16(za[kk], bh, acc[ct], 0, 0, 0);
        }
    }

    float bbv = bb[0];
    int r0 = rowBase + w * 16 + ((lane >> 4) << 2);
    float pos[4] = {0.f, 0.f, 0.f, 0.f}, neg[4] = {0.f, 0.f, 0.f, 0.f};
    #pragma unroll
    for (int r = 0; r < 4; ++r) {
        int gr = (r0 + r < NN) ? r0 + r : NN - 1;
        int pr = perm[gr];
        const unsigned short* zr = &zbf[(size_t)gr * HD];
        const unsigned short* zp = &zbf[(size_t)pr * HD];
        #pragma unroll
        for (int ct = 0; ct < 8; ++ct) {
            float tv = acc[ct][r];
            int col = ct * 16 + (lane & 15);
            pos[r] += tv * b2f(zr[col]);
            neg[r] += tv * b2f(zp[col]);
        }
    }
    #pragma unroll
    for (int r = 0; r < 4; ++r) {
        #pragma unroll
        for (int off = 1; off < 16; off <<= 1) {
            pos[r] += __shfl_xor(pos[r], off);
            neg[r] += __shfl_xor(neg[r], off);
        }
    }
    if ((lane & 15) == 0) {
        #pragma unroll
        for (int r = 0; r < 4; ++r) {
            int gr = r0 + r;
            if (gr < NN) {
                out[gr] = pos[r] + bbv;
                out[NN + gr] = neg[r] + bbv;
            }
        }
    }
}

extern "C" void kernel_launch(void* const* d_in, const int* in_sizes, int n_in,
                              void* d_out, int out_size, void* d_ws, size_t ws_size,
                              hipStream_t stream) {
    const float* x    = (const float*)d_in[0];
    const float* W    = (const float*)d_in[1];
    const float* b    = (const float*)d_in[2];
    const float* Wb   = (const float*)d_in[3];
    const float* bb   = (const float*)d_in[4];
    const int*   ei   = (const int*)d_in[5];
    const int*   perm = (const int*)d_in[6];
    float* out = (float*)d_out;

    char* ws = (char*)d_ws;
    int*            cursor   = (int*)(ws + 0);               // 4 KB
    float*          dinv     = (float*)(ws + 0x1000);        // 200 KB
    int*            rowstart = (int*)(ws + 0x33000);         // 200 KB
    int*            degi     = (int*)(ws + 0x65000);         // 200 KB
    unsigned short* csr      = (unsigned short*)(ws + 0x97000);   // 1.6 MB
    unsigned*       binned   = (unsigned*)(ws + 0x240000);   // 3.6 MB
    unsigned short* Wtg      = (unsigned short*)(ws + 0x5B0000);  // 35 KB
    unsigned short* Wbth     = (unsigned short*)(ws + 0x5C0000);  // 35 KB
    unsigned short* ybf      = (unsigned short*)(ws + 0x600000);  // 12.8 MB
    unsigned short* zbf      = (unsigned short*)(ws + 0x2000000); // 12.8 MB

    k_prep<<<(HD * HD + 255) / 256, 256, 0, stream>>>(W, Wb, cursor, Wtg, Wbth);
    k_fused1<<<GEMM_BLOCKS + BIN_BLOCKS, 256, 0, stream>>>(x, Wtg, ybf, ei, cursor, binned);
    k_csr<<<NBINS, 512, 0, stream>>>(binned, cursor, csr, rowstart, degi, dinv);
    k_gather<<<(NN + 15) / 16, 256, 0, stream>>>(csr, rowstart, degi, dinv, ybf, b, zbf);
    k_bilinear<<<GEMM_BLOCKS, 256, 0, stream>>>(zbf, Wbth, bb, perm, out);
}

// Round 12
// 85.976 us; speedup vs baseline: 1.4371x; 1.4371x over previous
//
#include <hip/hip_runtime.h>
#include <hip/hip_bf16.h>

#define NN 50000
#define NE 800000
#define HD 128
#define WPAD 136                // transposed-W LDS/global row stride (shorts), 16B-aligned

#define BINSH 9                 // 512 nodes per coarse bin
#define NBINS 98                // ceil(50000/512)
#define BINCAP 9216             // slop capacity (mean 8163, 11.6 sigma)
#define CHUNK 1024              // edges per binplace block (782 blocks)
#define MAXBIN 9216

#define GEMM_BLOCKS ((NN + 63) / 64)          // 782
#define BIN_BLOCKS  ((NE + CHUNK - 1) / CHUNK) // 782

typedef __attribute__((ext_vector_type(8))) short bf16x8;
typedef __attribute__((ext_vector_type(4))) float f32x4;

// f32 -> bf16 round-to-nearest-even
__device__ inline unsigned short f2bf(float f) {
    union { float f; unsigned u; } c; c.f = f;
    unsigned r = c.u + 0x7fff + ((c.u >> 16) & 1);
    return (unsigned short)(r >> 16);
}

__device__ inline float bflo(unsigned u) { return __uint_as_float(u << 16); }
__device__ inline float bfhi(unsigned u) { return __uint_as_float(u & 0xffff0000u); }
__device__ inline float b2f(unsigned short u) { return __uint_as_float(((unsigned)u) << 16); }

// ---------------- prep: cursor init + W^T bf16 + Wb^T bf16 tables ----------------
__global__ __launch_bounds__(256) void k_prep(
        const float* __restrict__ W, const float* __restrict__ Wb, int* cursor,
        unsigned short* __restrict__ Wtg, unsigned short* __restrict__ Wbth) {
    int t = threadIdx.x;
    if (blockIdx.x == 0 && t < NBINS) cursor[t] = t * BINCAP;
    int idx = blockIdx.x * 256 + t;
    if (idx < HD * HD) {
        int h = idx >> 7, c = idx & 127;        // W[h][c]
        Wtg[c * WPAD + h] = f2bf(W[idx]);
        Wbth[c * WPAD + h] = f2bf(Wb[idx]);
    }
}

// ---------------- fused: blocks [0,782) MFMA GEMM, blocks [782,1564) edge binning ----------------
__global__ __launch_bounds__(256) void k_fused1(
        const float* __restrict__ x, const unsigned short* __restrict__ Wtg,
        unsigned short* __restrict__ ybf,
        const int* __restrict__ ei, int* cursor, unsigned* __restrict__ binned) {
    __shared__ union {
        unsigned short Wt[HD * WPAD];           // 34816 B
        struct {
            unsigned stage[CHUNK];
            unsigned char sbin[CHUNK];
            int hist[NBINS], base[NBINS], cur[NBINS], gbase[NBINS];
        } p;
    } sh;
    int t = threadIdx.x;

    if (blockIdx.x < GEMM_BLOCKS) {
        // ---- GEMM: ybf = bf16(x @ W)  (dinv applied later in gather) ----
        int rowBase = blockIdx.x * 64;
        const uint4* src = (const uint4*)Wtg;
        uint4* dst = (uint4*)sh.Wt;
        #pragma unroll
        for (int i = 0; i < 9; ++i) {
            int f = t + i * 256;
            if (f < (HD * WPAD * 2) / 16) dst[f] = src[f];
        }
        __syncthreads();

        int w = t >> 6, lane = t & 63;
        int row = rowBase + w * 16 + (lane & 15);
        int rowc = row < NN ? row : NN - 1;
        int kbase = (lane >> 4) * 8;

        bf16x8 ah[4];
        const float* xrow = &x[(size_t)rowc * HD];
        #pragma unroll
        for (int kk = 0; kk < 4; ++kk) {
            float4 u0 = *(const float4*)(xrow + kk * 32 + kbase);
            float4 u1 = *(const float4*)(xrow + kk * 32 + kbase + 4);
            ah[kk][0] = (short)f2bf(u0.x); ah[kk][1] = (short)f2bf(u0.y);
            ah[kk][2] = (short)f2bf(u0.z); ah[kk][3] = (short)f2bf(u0.w);
            ah[kk][4] = (short)f2bf(u1.x); ah[kk][5] = (short)f2bf(u1.y);
            ah[kk][6] = (short)f2bf(u1.z); ah[kk][7] = (short)f2bf(u1.w);
        }

        f32x4 acc[8];
        #pragma unroll
        for (int ct = 0; ct < 8; ++ct) acc[ct] = (f32x4){0.f, 0.f, 0.f, 0.f};
        #pragma unroll
        for (int kk = 0; kk < 4; ++kk) {
            #pragma unroll
            for (int ct = 0; ct < 8; ++ct) {
                bf16x8 bfr = *(const bf16x8*)&sh.Wt[(ct * 16 + (lane & 15)) * WPAD + kk * 32 + kbase];
                acc[ct] = __builtin_amdgcn_mfma_f32_16x16x32_bf16(ah[kk], bfr, acc[ct], 0, 0, 0);
            }
        }

        int r0 = rowBase + w * 16 + ((lane >> 4) << 2);
        #pragma unroll
        for (int r = 0; r < 4; ++r) {
            int gr = r0 + r;
            if (gr >= NN) continue;
            size_t basei = (size_t)gr * HD;
            #pragma unroll
            for (int ct = 0; ct < 8; ++ct)
                ybf[basei + ct * 16 + (lane & 15)] = f2bf(acc[ct][r]);
        }
    } else {
        // ---- binplace: bin edges by dst>>9, coalesced writes ----
        int e0 = (blockIdx.x - GEMM_BLOCKS) * CHUNK;
        int nE = NE - e0; if (nE > CHUNK) nE = CHUNK;

        if (t < NBINS) sh.p.hist[t] = 0;
        __syncthreads();

        unsigned keys[CHUNK / 256], packs[CHUNK / 256];
        #pragma unroll
        for (int i = 0; i < CHUNK / 256; ++i) {
            int li = i * 256 + t;
            keys[i] = 0xffffffffu;
            if (li < nE) {
                int e = e0 + li;
                unsigned s = (unsigned)ei[e];
                unsigned d = (unsigned)ei[NE + e];
                if (s < NN && d < NN) {
                    keys[i] = d >> BINSH;
                    packs[i] = (s << BINSH) | (d & ((1u << BINSH) - 1));
                    atomicAdd(&sh.p.hist[keys[i]], 1);
                }
            }
        }
        __syncthreads();
        if (t == 0) { int a = 0; for (int b = 0; b < NBINS; ++b) { sh.p.base[b] = a; a += sh.p.hist[b]; } }
        __syncthreads();
        if (t < NBINS) {
            sh.p.cur[t] = sh.p.base[t];
            if (sh.p.hist[t] > 0) sh.p.gbase[t] = atomicAdd(&cursor[t], sh.p.hist[t]);
        }
        __syncthreads();
        #pragma unroll
        for (int i = 0; i < CHUNK / 256; ++i) {
            if (keys[i] != 0xffffffffu) {
                int p = atomicAdd(&sh.p.cur[keys[i]], 1);
                sh.p.stage[p] = packs[i];
                sh.p.sbin[p] = (unsigned char)keys[i];
            }
        }
        __syncthreads();
        int tot = sh.p.cur[NBINS - 1];
        for (int j = t; j < tot; j += 256) {
            unsigned b = sh.p.sbin[j];
            binned[sh.p.gbase[b] + (j - sh.p.base[b])] = sh.p.stage[j];
        }
    }
}

// ---------------- pass 2: per-bin sort -> CSR (u16 src), deg/dinv/rowstart ----------------
__global__ __launch_bounds__(512) void k_csr(
        const unsigned* __restrict__ binned, const int* __restrict__ cursor,
        unsigned short* __restrict__ csr, int* __restrict__ rowstart,
        int* __restrict__ degi, float* __restrict__ dinv) {
    __shared__ unsigned ent[MAXBIN];
    __shared__ unsigned short outv[MAXBIN];
    __shared__ int hist[512], rs[512], cur[512];
    __shared__ int sizes[NBINS];
    int t = threadIdx.x, b = blockIdx.x;

    if (t < NBINS) sizes[t] = cursor[t] - t * BINCAP;
    __syncthreads();
    int bsize = sizes[b]; if (bsize > MAXBIN) bsize = MAXBIN;
    int bstart = 0;
    for (int i = 0; i < b; ++i) bstart += sizes[i];

    for (int j = t; j < bsize; j += 512) ent[j] = binned[b * BINCAP + j];
    if (t < 512) hist[t] = 0;
    __syncthreads();
    for (int j = t; j < bsize; j += 512) atomicAdd(&hist[ent[j] & 511], 1);
    __syncthreads();
    if (t == 0) { int a = 0; for (int k = 0; k < 512; ++k) { rs[k] = a; a += hist[k]; } }
    __syncthreads();
    if (t < 512) {
        cur[t] = rs[t];
        int g = (b << BINSH) + t;
        if (g < NN) {
            rowstart[g] = bstart + rs[t];
            degi[g] = hist[t];
            dinv[g] = rsqrtf((float)(hist[t] + 1));
        }
    }
    __syncthreads();
    for (int j = t; j < bsize; j += 512) {
        unsigned v = ent[j];
        int p = atomicAdd(&cur[v & 511], 1);
        outv[p] = (unsigned short)(v >> BINSH);
    }
    __syncthreads();
    for (int j = t; j < bsize; j += 512) csr[bstart + j] = outv[j];
}

// ---------------- gather: zbf[n] = bf16(dinv[n]*(y[n]*dinv[n] + sum y[s]*dinv[s]) + b) ----------------
// 16 lanes per node, 8 cols (16 B) per lane. Tail-free 4-deep blocks: clamped
// indices + zero weights; no serial remainder; VGPR stays under the 64 cliff.
__global__ __launch_bounds__(256) void k_gather(
        const unsigned short* __restrict__ csr, const int* __restrict__ rowstart,
        const int* __restrict__ degi, const float* __restrict__ dinv,
        const unsigned short* __restrict__ ybf, const float* __restrict__ b,
        unsigned short* __restrict__ zbf) {
    int t = threadIdx.x;
    int n = blockIdx.x * 16 + (t >> 4);
    int lane = t & 15;
    if (n >= NN) return;
    int c = lane * 8;

    float dvn = dinv[n];
    float acc[8];
    {
        uint4 q = *(const uint4*)&ybf[(size_t)n * HD + c];
        acc[0] = bflo(q.x) * dvn; acc[1] = bfhi(q.x) * dvn;
        acc[2] = bflo(q.y) * dvn; acc[3] = bfhi(q.y) * dvn;
        acc[4] = bflo(q.z) * dvn; acc[5] = bfhi(q.z) * dvn;
        acc[6] = bflo(q.w) * dvn; acc[7] = bfhi(q.w) * dvn;
    }
    int beg = rowstart[n];
    int dg = degi[n];
    int nb = (dg + 3) >> 2;     // 4-edge blocks (0 if dg==0)

    for (int ib = 0; ib < nb; ++ib) {
        int i0 = ib * 4;
        int ss[4];
        bool live[4];
        #pragma unroll
        for (int u = 0; u < 4; ++u) {
            int ii = i0 + u;
            live[u] = ii < dg;
            int j = live[u] ? ii : dg - 1;     // clamp (dup of last edge, L1 hit)
            ss[u] = csr[beg + j];
        }
        float dd[4];
        uint4 q[4];
        #pragma unroll
        for (int u = 0; u < 4; ++u) {
            dd[u] = live[u] ? dinv[ss[u]] : 0.f;   // zero weight kills clamped dups
            q[u] = *(const uint4*)&ybf[(size_t)ss[u] * HD + c];
        }
        #pragma unroll
        for (int u = 0; u < 4; ++u) {
            acc[0] += bflo(q[u].x) * dd[u]; acc[1] += bfhi(q[u].x) * dd[u];
            acc[2] += bflo(q[u].y) * dd[u]; acc[3] += bfhi(q[u].y) * dd[u];
            acc[4] += bflo(q[u].z) * dd[u]; acc[5] += bfhi(q[u].z) * dd[u];
            acc[6] += bflo(q[u].w) * dd[u]; acc[7] += bfhi(q[u].w) * dd[u];
        }
    }

    float4 bv0 = *(const float4*)&b[c];
    float4 bv1 = *(const float4*)&b[c + 4];
    unsigned o0 = (unsigned)f2bf(acc[0] * dvn + bv0.x) | ((unsigned)f2bf(acc[1] * dvn + bv0.y) << 16);
    unsigned o1 = (unsigned)f2bf(acc[2] * dvn + bv0.z) | ((unsigned)f2bf(acc[3] * dvn + bv0.w) << 16);
    unsigned o2 = (unsigned)f2bf(acc[4] * dvn + bv1.x) | ((unsigned)f2bf(acc[5] * dvn + bv1.y) << 16);
    unsigned o3 = (unsigned)f2bf(acc[6] * dvn + bv1.z) | ((unsigned)f2bf(acc[7] * dvn + bv1.w) << 16);
    uint4 o = make_uint4(o0, o1, o2, o3);
    *(uint4*)&zbf[(size_t)n * HD + c] = o;
}

// ---------------- MFMA bilinear: t = zbf@Wb (1-pass); pos=<t,z>, neg=<t,z[perm]> ----------------
__global__ __launch_bounds__(256) void k_bilinear(
        const unsigned short* __restrict__ zbf,
        const unsigned short* __restrict__ Wbth,
        const float* __restrict__ bb, const int* __restrict__ perm,
        float* __restrict__ out) {
    __shared__ unsigned short Wth[HD * WPAD];   // Wb^T bf16, 34.8 KB
    int t = threadIdx.x;
    int rowBase = blockIdx.x * 64;

    {
        const uint4* shp = (const uint4*)Wbth;
        uint4* dh = (uint4*)Wth;
        #pragma unroll
        for (int i = 0; i < 9; ++i) {
            int f = t + i * 256;
            if (f < (HD * WPAD * 2) / 16) dh[f] = shp[f];
        }
    }
    __syncthreads();

    int w = t >> 6, lane = t & 63;
    int row = rowBase + w * 16 + (lane & 15);
    int rowc = row < NN ? row : NN - 1;
    int kbase = (lane >> 4) * 8;

    bf16x8 za[4];
    const unsigned short* zrow = &zbf[(size_t)rowc * HD];
    #pragma unroll
    for (int kk = 0; kk < 4; ++kk)
        za[kk] = *(const bf16x8*)&zrow[kk * 32 + kbase];

    f32x4 acc[8];
    #pragma unroll
    for (int ct = 0; ct < 8; ++ct) acc[ct] = (f32x4){0.f, 0.f, 0.f, 0.f};
    #pragma unroll
    for (int kk = 0; kk < 4; ++kk) {
        #pragma unroll
        for (int ct = 0; ct < 8; ++ct) {
            bf16x8 bh = *(const bf16x8*)&Wth[(ct * 16 + (lane & 15)) * WPAD + kk * 32 + kbase];
            acc[ct] = __builtin_amdgcn_mfma_f32_16x16x32_bf16(za[kk], bh, acc[ct], 0, 0, 0);
        }
    }

    float bbv = bb[0];
    int r0 = rowBase + w * 16 + ((lane >> 4) << 2);
    float pos[4] = {0.f, 0.f, 0.f, 0.f}, neg[4] = {0.f, 0.f, 0.f, 0.f};
    #pragma unroll
    for (int r = 0; r < 4; ++r) {
        int gr = (r0 + r < NN) ? r0 + r : NN - 1;
        int pr = perm[gr];
        const unsigned short* zr = &zbf[(size_t)gr * HD];
        const unsigned short* zp = &zbf[(size_t)pr * HD];
        #pragma unroll
        for (int ct = 0; ct < 8; ++ct) {
            float tv = acc[ct][r];
            int col = ct * 16 + (lane & 15);
            pos[r] += tv * b2f(zr[col]);
            neg[r] += tv * b2f(zp[col]);
        }
    }
    #pragma unroll
    for (int r = 0; r < 4; ++r) {
        #pragma unroll
        for (int off = 1; off < 16; off <<= 1) {
            pos[r] += __shfl_xor(pos[r], off);
            neg[r] += __shfl_xor(neg[r], off);
        }
    }
    if ((lane & 15) == 0) {
        #pragma unroll
        for (int r = 0; r < 4; ++r) {
            int gr = r0 + r;
            if (gr < NN) {
                out[gr] = pos[r] + bbv;
                out[NN + gr] = neg[r] + bbv;
            }
        }
    }
}

extern "C" void kernel_launch(void* const* d_in, const int* in_sizes, int n_in,
                              void* d_out, int out_size, void* d_ws, size_t ws_size,
                              hipStream_t stream) {
    const float* x    = (const float*)d_in[0];
    const float* W    = (const float*)d_in[1];
    const float* b    = (const float*)d_in[2];
    const float* Wb   = (const float*)d_in[3];
    const float* bb   = (const float*)d_in[4];
    const int*   ei   = (const int*)d_in[5];
    const int*   perm = (const int*)d_in[6];
    float* out = (float*)d_out;

    char* ws = (char*)d_ws;
    int*            cursor   = (int*)(ws + 0);               // 4 KB
    float*          dinv     = (float*)(ws + 0x1000);        // 200 KB
    int*            rowstart = (int*)(ws + 0x33000);         // 200 KB
    int*            degi     = (int*)(ws + 0x65000);         // 200 KB
    unsigned short* csr      = (unsigned short*)(ws + 0x97000);   // 1.6 MB
    unsigned*       binned   = (unsigned*)(ws + 0x240000);   // 3.6 MB
    unsigned short* Wtg      = (unsigned short*)(ws + 0x5B0000);  // 35 KB
    unsigned short* Wbth     = (unsigned short*)(ws + 0x5C0000);  // 35 KB
    unsigned short* ybf      = (unsigned short*)(ws + 0x600000);  // 12.8 MB
    unsigned short* zbf      = (unsigned short*)(ws + 0x2000000); // 12.8 MB

    k_prep<<<(HD * HD + 255) / 256, 256, 0, stream>>>(W, Wb, cursor, Wtg, Wbth);
    k_fused1<<<GEMM_BLOCKS + BIN_BLOCKS, 256, 0, stream>>>(x, Wtg, ybf, ei, cursor, binned);
    k_csr<<<NBINS, 512, 0, stream>>>(binned, cursor, csr, rowstart, degi, dinv);
    k_gather<<<(NN + 15) / 16, 256, 0, stream>>>(csr, rowstart, degi, dinv, ybf, b, zbf);
    k_bilinear<<<GEMM_BLOCKS, 256, 0, stream>>>(zbf, Wbth, bb, perm, out);
}

// Round 13
// 83.414 us; speedup vs baseline: 1.4812x; 1.0307x over previous
//
#include <hip/hip_runtime.h>
#include <hip/hip_bf16.h>

#define NN 50000
#define NE 800000
#define HD 128
#define WPAD 136                // transposed-W LDS/global row stride (shorts), 16B-aligned

#define BINSH 9                 // 512 nodes per coarse bin
#define NBINS 98                // ceil(50000/512)
#define BINCAP 9216             // slop capacity (mean 8163, 11.6 sigma)
#define CHUNK 1024              // edges per binplace block (782 blocks)
#define MAXBIN 9216

#define GEMM_BLOCKS ((NN + 63) / 64)          // 782
#define BIN_BLOCKS  ((NE + CHUNK - 1) / CHUNK) // 782

typedef __attribute__((ext_vector_type(8))) short bf16x8;
typedef __attribute__((ext_vector_type(4))) float f32x4;

// f32 -> bf16 round-to-nearest-even
__device__ inline unsigned short f2bf(float f) {
    union { float f; unsigned u; } c; c.f = f;
    unsigned r = c.u + 0x7fff + ((c.u >> 16) & 1);
    return (unsigned short)(r >> 16);
}

__device__ inline float bflo(unsigned u) { return __uint_as_float(u << 16); }
__device__ inline float bfhi(unsigned u) { return __uint_as_float(u & 0xffff0000u); }
__device__ inline float b2f(unsigned short u) { return __uint_as_float(((unsigned)u) << 16); }

// ---------------- prep: cursor init + W^T bf16 + Wb^T bf16 tables ----------------
__global__ __launch_bounds__(256) void k_prep(
        const float* __restrict__ W, const float* __restrict__ Wb, int* cursor,
        unsigned short* __restrict__ Wtg, unsigned short* __restrict__ Wbth) {
    int t = threadIdx.x;
    if (blockIdx.x == 0 && t < NBINS) cursor[t] = t * BINCAP;
    int idx = blockIdx.x * 256 + t;
    if (idx < HD * HD) {
        int h = idx >> 7, c = idx & 127;        // W[h][c]
        Wtg[c * WPAD + h] = f2bf(W[idx]);
        Wbth[c * WPAD + h] = f2bf(Wb[idx]);
    }
}

// ---------------- fused: blocks [0,782) MFMA GEMM, blocks [782,1564) edge binning ----------------
__global__ __launch_bounds__(256) void k_fused1(
        const float* __restrict__ x, const unsigned short* __restrict__ Wtg,
        unsigned short* __restrict__ ybf,
        const int* __restrict__ ei, int* cursor, unsigned* __restrict__ binned) {
    __shared__ union __align__(16) {
        unsigned short Wt[HD * WPAD];           // 34816 B (also reused as C-tile)
        struct {
            unsigned stage[CHUNK];
            unsigned char sbin[CHUNK];
            int hist[NBINS], base[NBINS], cur[NBINS], gbase[NBINS];
        } p;
    } sh;
    int t = threadIdx.x;

    if (blockIdx.x < GEMM_BLOCKS) {
        // ---- GEMM: ybf = bf16(x @ W)  (dinv applied later in gather) ----
        int rowBase = blockIdx.x * 64;
        const uint4* src = (const uint4*)Wtg;
        uint4* dst = (uint4*)sh.Wt;
        #pragma unroll
        for (int i = 0; i < 9; ++i) {
            int f = t + i * 256;
            if (f < (HD * WPAD * 2) / 16) dst[f] = src[f];
        }
        __syncthreads();

        int w = t >> 6, lane = t & 63;
        int row = rowBase + w * 16 + (lane & 15);
        int rowc = row < NN ? row : NN - 1;
        int kbase = (lane >> 4) * 8;

        bf16x8 ah[4];
        const float* xrow = &x[(size_t)rowc * HD];
        #pragma unroll
        for (int kk = 0; kk < 4; ++kk) {
            float4 u0 = *(const float4*)(xrow + kk * 32 + kbase);
            float4 u1 = *(const float4*)(xrow + kk * 32 + kbase + 4);
            ah[kk][0] = (short)f2bf(u0.x); ah[kk][1] = (short)f2bf(u0.y);
            ah[kk][2] = (short)f2bf(u0.z); ah[kk][3] = (short)f2bf(u0.w);
            ah[kk][4] = (short)f2bf(u1.x); ah[kk][5] = (short)f2bf(u1.y);
            ah[kk][6] = (short)f2bf(u1.z); ah[kk][7] = (short)f2bf(u1.w);
        }

        f32x4 acc[8];
        #pragma unroll
        for (int ct = 0; ct < 8; ++ct) acc[ct] = (f32x4){0.f, 0.f, 0.f, 0.f};
        #pragma unroll
        for (int kk = 0; kk < 4; ++kk) {
            #pragma unroll
            for (int ct = 0; ct < 8; ++ct) {
                bf16x8 bfr = *(const bf16x8*)&sh.Wt[(ct * 16 + (lane & 15)) * WPAD + kk * 32 + kbase];
                acc[ct] = __builtin_amdgcn_mfma_f32_16x16x32_bf16(ah[kk], bfr, acc[ct], 0, 0, 0);
            }
        }

        // epilogue: LDS-bounce C tile (reuse Wt region) for coalesced uint4 stores
        __syncthreads();                       // all waves done reading Wt
        unsigned short* ct_lds = sh.Wt;        // 64 rows x WPAD shorts
        int lr0 = w * 16 + ((lane >> 4) << 2); // local row of acc[.][0]
        #pragma unroll
        for (int r = 0; r < 4; ++r) {
            #pragma unroll
            for (int ct = 0; ct < 8; ++ct)
                ct_lds[(lr0 + r) * WPAD + ct * 16 + (lane & 15)] = f2bf(acc[ct][r]);
        }
        __syncthreads();
        #pragma unroll
        for (int it = 0; it < 4; ++it) {
            int rr = (t >> 4) + it * 16;       // 16 rows per iteration
            int cc = (t & 15) * 8;             // 8 shorts = 16 B per lane
            int gr2 = rowBase + rr;
            if (gr2 < NN)
                *(uint4*)&ybf[(size_t)gr2 * HD + cc] = *(const uint4*)&ct_lds[rr * WPAD + cc];
        }
    } else {
        // ---- binplace: bin edges by dst>>9, coalesced writes ----
        int e0 = (blockIdx.x - GEMM_BLOCKS) * CHUNK;
        int nE = NE - e0; if (nE > CHUNK) nE = CHUNK;

        if (t < NBINS) sh.p.hist[t] = 0;
        __syncthreads();

        unsigned keys[CHUNK / 256], packs[CHUNK / 256];
        #pragma unroll
        for (int i = 0; i < CHUNK / 256; ++i) {
            int li = i * 256 + t;
            keys[i] = 0xffffffffu;
            if (li < nE) {
                int e = e0 + li;
                unsigned s = (unsigned)ei[e];
                unsigned d = (unsigned)ei[NE + e];
                if (s < NN && d < NN) {
                    keys[i] = d >> BINSH;
                    packs[i] = (s << BINSH) | (d & ((1u << BINSH) - 1));
                    atomicAdd(&sh.p.hist[keys[i]], 1);
                }
            }
        }
        __syncthreads();
        if (t == 0) { int a = 0; for (int b = 0; b < NBINS; ++b) { sh.p.base[b] = a; a += sh.p.hist[b]; } }
        __syncthreads();
        if (t < NBINS) {
            sh.p.cur[t] = sh.p.base[t];
            if (sh.p.hist[t] > 0) sh.p.gbase[t] = atomicAdd(&cursor[t], sh.p.hist[t]);
        }
        __syncthreads();
        #pragma unroll
        for (int i = 0; i < CHUNK / 256; ++i) {
            if (keys[i] != 0xffffffffu) {
                int p = atomicAdd(&sh.p.cur[keys[i]], 1);
                sh.p.stage[p] = packs[i];
                sh.p.sbin[p] = (unsigned char)keys[i];
            }
        }
        __syncthreads();
        int tot = sh.p.cur[NBINS - 1];
        for (int j = t; j < tot; j += 256) {
            unsigned b = sh.p.sbin[j];
            binned[sh.p.gbase[b] + (j - sh.p.base[b])] = sh.p.stage[j];
        }
    }
}

// ---------------- pass 2: per-bin sort -> CSR (u16 src), deg/dinv/rowstart ----------------
__global__ __launch_bounds__(512) void k_csr(
        const unsigned* __restrict__ binned, const int* __restrict__ cursor,
        unsigned short* __restrict__ csr, int* __restrict__ rowstart,
        int* __restrict__ degi, float* __restrict__ dinv) {
    __shared__ unsigned ent[MAXBIN];
    __shared__ unsigned short outv[MAXBIN];
    __shared__ int hist[512], rs[512], cur[512];
    __shared__ int sizes[NBINS];
    int t = threadIdx.x, b = blockIdx.x;

    if (t < NBINS) sizes[t] = cursor[t] - t * BINCAP;
    __syncthreads();
    int bsize = sizes[b]; if (bsize > MAXBIN) bsize = MAXBIN;
    int bstart = 0;
    for (int i = 0; i < b; ++i) bstart += sizes[i];

    for (int j = t; j < bsize; j += 512) ent[j] = binned[b * BINCAP + j];
    if (t < 512) hist[t] = 0;
    __syncthreads();
    for (int j = t; j < bsize; j += 512) atomicAdd(&hist[ent[j] & 511], 1);
    __syncthreads();
    if (t == 0) { int a = 0; for (int k = 0; k < 512; ++k) { rs[k] = a; a += hist[k]; } }
    __syncthreads();
    if (t < 512) {
        cur[t] = rs[t];
        int g = (b << BINSH) + t;
        if (g < NN) {
            rowstart[g] = bstart + rs[t];
            degi[g] = hist[t];
            dinv[g] = rsqrtf((float)(hist[t] + 1));
        }
    }
    __syncthreads();
    for (int j = t; j < bsize; j += 512) {
        unsigned v = ent[j];
        int p = atomicAdd(&cur[v & 511], 1);
        outv[p] = (unsigned short)(v >> BINSH);
    }
    __syncthreads();
    for (int j = t; j < bsize; j += 512) csr[bstart + j] = outv[j];
}

// ---------------- gather: zbf[n] = bf16(dinv[n]*(y[n]*dinv[n] + sum y[s]*dinv[s]) + b) ----------------
// 16 lanes per node, 8 cols (16 B) per lane. Tail-free 4-deep blocks: clamped
// indices + zero weights; no serial remainder; VGPR stays under the 64 cliff.
__global__ __launch_bounds__(256) void k_gather(
        const unsigned short* __restrict__ csr, const int* __restrict__ rowstart,
        const int* __restrict__ degi, const float* __restrict__ dinv,
        const unsigned short* __restrict__ ybf, const float* __restrict__ b,
        unsigned short* __restrict__ zbf) {
    int t = threadIdx.x;
    int n = blockIdx.x * 16 + (t >> 4);
    int lane = t & 15;
    if (n >= NN) return;
    int c = lane * 8;

    float dvn = dinv[n];
    float acc[8];
    {
        uint4 q = *(const uint4*)&ybf[(size_t)n * HD + c];
        acc[0] = bflo(q.x) * dvn; acc[1] = bfhi(q.x) * dvn;
        acc[2] = bflo(q.y) * dvn; acc[3] = bfhi(q.y) * dvn;
        acc[4] = bflo(q.z) * dvn; acc[5] = bfhi(q.z) * dvn;
        acc[6] = bflo(q.w) * dvn; acc[7] = bfhi(q.w) * dvn;
    }
    int beg = rowstart[n];
    int dg = degi[n];
    int nb = (dg + 3) >> 2;     // 4-edge blocks (0 if dg==0)

    for (int ib = 0; ib < nb; ++ib) {
        int i0 = ib * 4;
        int ss[4];
        bool live[4];
        #pragma unroll
        for (int u = 0; u < 4; ++u) {
            int ii = i0 + u;
            live[u] = ii < dg;
            int j = live[u] ? ii : dg - 1;     // clamp (dup of last edge, L1 hit)
            ss[u] = csr[beg + j];
        }
        float dd[4];
        uint4 q[4];
        #pragma unroll
        for (int u = 0; u < 4; ++u) {
            dd[u] = live[u] ? dinv[ss[u]] : 0.f;   // zero weight kills clamped dups
            q[u] = *(const uint4*)&ybf[(size_t)ss[u] * HD + c];
        }
        #pragma unroll
        for (int u = 0; u < 4; ++u) {
            acc[0] += bflo(q[u].x) * dd[u]; acc[1] += bfhi(q[u].x) * dd[u];
            acc[2] += bflo(q[u].y) * dd[u]; acc[3] += bfhi(q[u].y) * dd[u];
            acc[4] += bflo(q[u].z) * dd[u]; acc[5] += bfhi(q[u].z) * dd[u];
            acc[6] += bflo(q[u].w) * dd[u]; acc[7] += bfhi(q[u].w) * dd[u];
        }
    }

    float4 bv0 = *(const float4*)&b[c];
    float4 bv1 = *(const float4*)&b[c + 4];
    unsigned o0 = (unsigned)f2bf(acc[0] * dvn + bv0.x) | ((unsigned)f2bf(acc[1] * dvn + bv0.y) << 16);
    unsigned o1 = (unsigned)f2bf(acc[2] * dvn + bv0.z) | ((unsigned)f2bf(acc[3] * dvn + bv0.w) << 16);
    unsigned o2 = (unsigned)f2bf(acc[4] * dvn + bv1.x) | ((unsigned)f2bf(acc[5] * dvn + bv1.y) << 16);
    unsigned o3 = (unsigned)f2bf(acc[6] * dvn + bv1.z) | ((unsigned)f2bf(acc[7] * dvn + bv1.w) << 16);
    uint4 o = make_uint4(o0, o1, o2, o3);
    *(uint4*)&zbf[(size_t)n * HD + c] = o;
}

// ---------------- MFMA bilinear: t = zbf@Wb (1-pass); pos=<t,z>, neg=<t,z[perm]> ----------------
__global__ __launch_bounds__(256) void k_bilinear(
        const unsigned short* __restrict__ zbf,
        const unsigned short* __restrict__ Wbth,
        const float* __restrict__ bb, const int* __restrict__ perm,
        float* __restrict__ out) {
    __shared__ unsigned short Wth[HD * WPAD];   // Wb^T bf16, 34.8 KB
    int t = threadIdx.x;
    int rowBase = blockIdx.x * 64;

    {
        const uint4* shp = (const uint4*)Wbth;
        uint4* dh = (uint4*)Wth;
        #pragma unroll
        for (int i = 0; i < 9; ++i) {
            int f = t + i * 256;
            if (f < (HD * WPAD * 2) / 16) dh[f] = shp[f];
        }
    }
    __syncthreads();

    int w = t >> 6, lane = t & 63;
    int row = rowBase + w * 16 + (lane & 15);
    int rowc = row < NN ? row : NN - 1;
    int kbase = (lane >> 4) * 8;

    bf16x8 za[4];
    const unsigned short* zrow = &zbf[(size_t)rowc * HD];
    #pragma unroll
    for (int kk = 0; kk < 4; ++kk)
        za[kk] = *(const bf16x8*)&zrow[kk * 32 + kbase];

    f32x4 acc[8];
    #pragma unroll
    for (int ct = 0; ct < 8; ++ct) acc[ct] = (f32x4){0.f, 0.f, 0.f, 0.f};
    #pragma unroll
    for (int kk = 0; kk < 4; ++kk) {
        #pragma unroll
        for (int ct = 0; ct < 8; ++ct) {
            bf16x8 bh = *(const bf16x8*)&Wth[(ct * 16 + (lane & 15)) * WPAD + kk * 32 + kbase];
            acc[ct] = __builtin_amdgcn_mfma_f32_16x16x32_bf16(za[kk], bh, acc[ct], 0, 0, 0);
        }
    }

    float bbv = bb[0];
    int r0 = rowBase + w * 16 + ((lane >> 4) << 2);
    float pos[4] = {0.f, 0.f, 0.f, 0.f}, neg[4] = {0.f, 0.f, 0.f, 0.f};
    #pragma unroll
    for (int r = 0; r < 4; ++r) {
        int gr = (r0 + r < NN) ? r0 + r : NN - 1;
        int pr = perm[gr];
        const unsigned short* zr = &zbf[(size_t)gr * HD];
        const unsigned short* zp = &zbf[(size_t)pr * HD];
        #pragma unroll
        for (int ct = 0; ct < 8; ++ct) {
            float tv = acc[ct][r];
            int col = ct * 16 + (lane & 15);
            pos[r] += tv * b2f(zr[col]);
            neg[r] += tv * b2f(zp[col]);
        }
    }
    #pragma unroll
    for (int r = 0; r < 4; ++r) {
        #pragma unroll
        for (int off = 1; off < 16; off <<= 1) {
            pos[r] += __shfl_xor(pos[r], off);
            neg[r] += __shfl_xor(neg[r], off);
        }
    }
    if ((lane & 15) == 0) {
        #pragma unroll
        for (int r = 0; r < 4; ++r) {
            int gr = r0 + r;
            if (gr < NN) {
                out[gr] = pos[r] + bbv;
                out[NN + gr] = neg[r] + bbv;
            }
        }
    }
}

extern "C" void kernel_launch(void* const* d_in, const int* in_sizes, int n_in,
                              void* d_out, int out_size, void* d_ws, size_t ws_size,
                              hipStream_t stream) {
    const float* x    = (const float*)d_in[0];
    const float* W    = (const float*)d_in[1];
    const float* b    = (const float*)d_in[2];
    const float* Wb   = (const float*)d_in[3];
    const float* bb   = (const float*)d_in[4];
    const int*   ei   = (const int*)d_in[5];
    const int*   perm = (const int*)d_in[6];
    float* out = (float*)d_out;

    char* ws = (char*)d_ws;
    int*            cursor   = (int*)(ws + 0);               // 4 KB
    float*          dinv     = (float*)(ws + 0x1000);        // 200 KB
    int*            rowstart = (int*)(ws + 0x33000);         // 200 KB
    int*            degi     = (int*)(ws + 0x65000);         // 200 KB
    unsigned short* csr      = (unsigned short*)(ws + 0x97000);   // 1.6 MB
    unsigned*       binned   = (unsigned*)(ws + 0x240000);   // 3.6 MB
    unsigned short* Wtg      = (unsigned short*)(ws + 0x5B0000);  // 35 KB
    unsigned short* Wbth     = (unsigned short*)(ws + 0x5C0000);  // 35 KB
    unsigned short* ybf      = (unsigned short*)(ws + 0x600000);  // 12.8 MB
    unsigned short* zbf      = (unsigned short*)(ws + 0x2000000); // 12.8 MB

    k_prep<<<(HD * HD + 255) / 256, 256, 0, stream>>>(W, Wb, cursor, Wtg, Wbth);
    k_fused1<<<GEMM_BLOCKS + BIN_BLOCKS, 256, 0, stream>>>(x, Wtg, ybf, ei, cursor, binned);
    k_csr<<<NBINS, 512, 0, stream>>>(binned, cursor, csr, rowstart, degi, dinv);
    k_gather<<<(NN + 15) / 16, 256, 0, stream>>>(csr, rowstart, degi, dinv, ybf, b, zbf);
    k_bilinear<<<GEMM_BLOCKS, 256, 0, stream>>>(zbf, Wbth, bb, perm, out);
}